// Round 2
// baseline (933.955 us; speedup 1.0000x reference)
//
#include <hip/hip_runtime.h>

typedef float v2f __attribute__((ext_vector_type(2)));

// Problem constants (from reference)
constexpr int I_N = 3, H_N = 2048, O_N = 2, S_N = 4, G_N = 7;
constexpr int B_N = 32, T_N = 512;
constexpr int TPB = 512;          // threads per block (8 waves)
constexpr int EPT = H_N / TPB;    // 4 consecutive h-elements per thread
constexpr float ALPHA_C = 0.2f;
constexpr float NSTD_C = 0.05f;
constexpr float TWO_LOG2E = 2.885390081777927f;  // 2*log2(e)

// tanh(x) = 1 - 2/(exp2(2*log2e*x)+1); inf-safe both ends, 1 mul + v_exp
__device__ __forceinline__ float fast_tanh(float x) {
  float e = __builtin_amdgcn_exp2f(x * TWO_LOG2E);
  return fmaf(-2.0f, __builtin_amdgcn_rcpf(e + 1.0f), 1.0f);
}

#define DPP_ADD(x, ctrl)                                                       \
  x += __int_as_float(__builtin_amdgcn_update_dpp(                             \
      0, __float_as_int(x), (ctrl), 0xf, 0xf, true))

__global__ __launch_bounds__(TPB) void rnn_fused(
    const float* __restrict__ input,   // (B,T,I)
    const float* __restrict__ noise,   // (B,T,H)
    const float* __restrict__ wi,      // (I,S,G)
    const float* __restrict__ unitwi,  // (I,S,1)
    const float* __restrict__ m_,      // (R,S,G)
    const float* __restrict__ n_,      // (R,S,G)
    const float* __restrict__ unitm,   // (R,S,1)
    const float* __restrict__ unitn,   // (R,S,1)
    const float* __restrict__ wo,      // (O,S,G)
    const float* __restrict__ h0,      // (S,G)
    const float* __restrict__ unith0,  // (S,1)
    const float* __restrict__ bias,    // (S,1)
    const float* __restrict__ gb,      // (G,H)
    const float* __restrict__ uv,      // (1,H)
    const float* __restrict__ sup,     // (S,H)
    float* __restrict__ out,           // (B,T,O)
    float* __restrict__ traj) {        // (B,T,H)
  const int tid = threadIdx.x;
  const int lane = tid & 63;
  const int b = blockIdx.x;
  const int hbase = tid * EPT;
  const int s = hbase >> 9;  // H/S = 512; all 4 elems share the same support

  // Triple-buffered global accumulators {a0,a1,o0,o1} + staged x
  __shared__ float4 bufs[3];
  __shared__ float4 xs4[T_N];  // x_t staged as float4 (w unused), 8 KB

  // ---- setup: per-element proxy constants (one-time) ----
  float cn0[EPT], cn1[EPT], cm0[EPT], cm1[EPT];
  float cw0[EPT], cw1[EPT], cw2[EPT];
  float co0[EPT], co1[EPT], cb[EPT], hh_[EPT], r[EPT];

  for (int e = 0; e < EPT; ++e) {
    const int hh = hbase + e;
    float gbh[G_N];
#pragma unroll
    for (int g = 0; g < G_N; ++g) gbh[g] = gb[g * H_N + hh];
    const float uvh = uv[hh];
    const float sv = sup[s * H_N + hh];

    auto comb = [&](const float* p, const float* up, int k) {
      float acc = up[k * S_N + s] * uvh;
#pragma unroll
      for (int g = 0; g < G_N; ++g)
        acc = fmaf(p[(k * S_N + s) * G_N + g], gbh[g], acc);
      return acc * sv;
    };
    auto combNoU = [&](const float* p, int k) {
      float acc = 0.0f;
#pragma unroll
      for (int g = 0; g < G_N; ++g)
        acc = fmaf(p[(k * S_N + s) * G_N + g], gbh[g], acc);
      return acc * sv;
    };

    cn0[e] = comb(n_, unitn, 0);
    cn1[e] = comb(n_, unitn, 1);
    cm0[e] = ALPHA_C * comb(m_, unitm, 0);
    cm1[e] = ALPHA_C * comb(m_, unitm, 1);
    cw0[e] = ALPHA_C * comb(wi, unitwi, 0);
    cw1[e] = ALPHA_C * comb(wi, unitwi, 1);
    cw2[e] = ALPHA_C * comb(wi, unitwi, 2);
    co0[e] = combNoU(wo, 0);
    co1[e] = combNoU(wo, 1);
    cb[e] = bias[s] * uvh * sv;
    hh_[e] = comb(h0, unith0, 0);
    r[e] = fast_tanh(hh_[e]);
  }

  // packed layouts
  v2f cnp[EPT], cop[EPT];            // value pairs {*,0 , *,1} for dots
  v2f cm0p[2], cm1p[2], cw0p[2], cw1p[2], cw2p[2], cbp[2];  // elem pairs
#pragma unroll
  for (int e = 0; e < EPT; ++e) {
    cnp[e] = (v2f){cn0[e], cn1[e]};
    cop[e] = (v2f){co0[e], co1[e]};
  }
#pragma unroll
  for (int p2 = 0; p2 < 2; ++p2) {
    cm0p[p2] = (v2f){cm0[2 * p2], cm0[2 * p2 + 1]};
    cm1p[p2] = (v2f){cm1[2 * p2], cm1[2 * p2 + 1]};
    cw0p[p2] = (v2f){cw0[2 * p2], cw0[2 * p2 + 1]};
    cw1p[p2] = (v2f){cw1[2 * p2], cw1[2 * p2 + 1]};
    cw2p[p2] = (v2f){cw2[2 * p2], cw2[2 * p2 + 1]};
    cbp[p2] = (v2f){cb[2 * p2], cb[2 * p2 + 1]};
  }
  v2f h01 = (v2f){hh_[0], hh_[1]};
  v2f h23 = (v2f){hh_[2], hh_[3]};

  const float* zp = noise + ((size_t)b * T_N) * H_N + hbase;
  const float* xp = input + ((size_t)b * T_N) * I_N;
  float* tp = traj + ((size_t)b * T_N) * H_N + hbase;
  float* op = out + ((size_t)b * T_N) * O_N;

  // stage x into LDS: thread t handles timestep t (TPB == T_N)
  {
    const float* xq = xp + tid * I_N;
    xs4[tid] = make_float4(xq[0], xq[1], xq[2], 0.0f);
  }
  if (tid == 0) {
    bufs[0] = make_float4(0.f, 0.f, 0.f, 0.f);
    bufs[1] = make_float4(0.f, 0.f, 0.f, 0.f);
  }

  // depth-2 z prefetch
  float4 z0 = *(const float4*)zp;
  float4 z1 = *(const float4*)(zp + H_N);

  __builtin_amdgcn_s_waitcnt(0xC07F);  // lgkmcnt(0)
  __builtin_amdgcn_s_barrier();
  __asm__ volatile("" ::: "memory");

  float4 xv = xs4[0];  // x_0 (broadcast LDS read)
  int pb = 0, pz = 2;

#pragma unroll 2
  for (int t = 0; t < T_N; ++t) {
    // prefetch z_{t+2} (HBM, depth 2) and x_{t+1} (LDS, depth 1)
    const int tz = (t + 2 < T_N) ? t + 2 : T_N - 1;
    float4 zn = *(const float4*)(zp + (size_t)tz * H_N);
    const int tx = (t + 1 < T_N) ? t + 1 : T_N - 1;
    float4 xn = xs4[tx];

    // reduce-independent part of the update: bias + noise + x·wi
    v2f z01 = (v2f){z0.x, z0.y}, z23 = (v2f){z0.z, z0.w};
    v2f pre01 = cbp[0];
    pre01 += NSTD_C * z01;
    pre01 += xv.x * cw0p[0];
    pre01 += xv.y * cw1p[0];
    pre01 += xv.z * cw2p[0];
    v2f pre23 = cbp[1];
    pre23 += NSTD_C * z23;
    pre23 += xv.x * cw0p[1];
    pre23 += xv.y * cw1p[1];
    pre23 += xv.z * cw2p[1];

    // 4 dot-partials: a0,a1 (recurrence), o0,o1 (out_{t-1})
    v2f accA = (v2f){0.f, 0.f}, accO = (v2f){0.f, 0.f};
#pragma unroll
    for (int e = 0; e < EPT; ++e) {
      v2f rr = (v2f){r[e], r[e]};
      accA += rr * cnp[e];
      accO += rr * cop[e];
    }
    float pa0 = accA.x, pa1 = accA.y, po0 = accO.x, po1 = accO.y;

    // 4-step row16 prefix reduce -> lanes 15/31/47/63 hold row sums
    DPP_ADD(pa0, 0x111); DPP_ADD(pa0, 0x112); DPP_ADD(pa0, 0x114); DPP_ADD(pa0, 0x118);
    DPP_ADD(pa1, 0x111); DPP_ADD(pa1, 0x112); DPP_ADD(pa1, 0x114); DPP_ADD(pa1, 0x118);
    DPP_ADD(po0, 0x111); DPP_ADD(po0, 0x112); DPP_ADD(po0, 0x114); DPP_ADD(po0, 0x118);
    DPP_ADD(po1, 0x111); DPP_ADD(po1, 0x112); DPP_ADD(po1, 0x114); DPP_ADD(po1, 0x118);

    float* bp = (float*)&bufs[pb];
    if ((lane & 15) == 15) {
      atomicAdd(bp + 0, pa0);
      atomicAdd(bp + 1, pa1);
      atomicAdd(bp + 2, po0);
      atomicAdd(bp + 3, po1);
    }
    __builtin_amdgcn_s_waitcnt(0xC07F);  // lgkmcnt(0) only; no vmcnt drain
    __builtin_amdgcn_s_barrier();
    __asm__ volatile("" ::: "memory");

    const float4 res = *(const float4*)&bufs[pb];  // broadcast read
    const float a0 = res.x, a1 = res.y;

    if (tid == 0) {
      if (t > 0) ((float2*)op)[t - 1] = make_float2(res.z, res.w);
      bufs[pz] = make_float4(0.f, 0.f, 0.f, 0.f);  // zero 2 steps ahead
    }

    // h <- 0.8h + pre + a0*cm0 + a1*cm1
    h01 = 0.8f * h01 + pre01;
    h01 += a0 * cm0p[0];
    h01 += a1 * cm1p[0];
    h23 = 0.8f * h23 + pre23;
    h23 += a0 * cm0p[1];
    h23 += a1 * cm1p[1];

    *(float4*)(tp + (size_t)t * H_N) = make_float4(h01.x, h01.y, h23.x, h23.y);

    r[0] = fast_tanh(h01.x);
    r[1] = fast_tanh(h01.y);
    r[2] = fast_tanh(h23.x);
    r[3] = fast_tanh(h23.y);

    z0 = z1; z1 = zn; xv = xn;
    pb = (pb == 2) ? 0 : pb + 1;
    pz = (pz == 2) ? 0 : pz + 1;
  }

  // tail: out[T-1] = tanh(h_T) @ wo ; bufs[pb] is already zeroed
  {
    v2f accO = (v2f){0.f, 0.f};
#pragma unroll
    for (int e = 0; e < EPT; ++e) {
      v2f rr = (v2f){r[e], r[e]};
      accO += rr * cop[e];
    }
    float po0 = accO.x, po1 = accO.y;
    DPP_ADD(po0, 0x111); DPP_ADD(po0, 0x112); DPP_ADD(po0, 0x114); DPP_ADD(po0, 0x118);
    DPP_ADD(po1, 0x111); DPP_ADD(po1, 0x112); DPP_ADD(po1, 0x114); DPP_ADD(po1, 0x118);
    float* bp = (float*)&bufs[pb];
    if ((lane & 15) == 15) {
      atomicAdd(bp + 2, po0);
      atomicAdd(bp + 3, po1);
    }
    __builtin_amdgcn_s_waitcnt(0xC07F);
    __builtin_amdgcn_s_barrier();
    __asm__ volatile("" ::: "memory");
    if (tid == 0) {
      const float4 res = *(const float4*)&bufs[pb];
      ((float2*)op)[T_N - 1] = make_float2(res.z, res.w);
    }
  }
}

extern "C" void kernel_launch(void* const* d_in, const int* in_sizes, int n_in,
                              void* d_out, int out_size, void* d_ws, size_t ws_size,
                              hipStream_t stream) {
  const float* input  = (const float*)d_in[0];
  const float* noise  = (const float*)d_in[1];
  const float* wi     = (const float*)d_in[2];
  const float* unitwi = (const float*)d_in[3];
  const float* m_     = (const float*)d_in[4];
  const float* n_     = (const float*)d_in[5];
  const float* unitm  = (const float*)d_in[6];
  const float* unitn  = (const float*)d_in[7];
  const float* wo     = (const float*)d_in[8];
  const float* h0     = (const float*)d_in[9];
  const float* unith0 = (const float*)d_in[10];
  const float* bias   = (const float*)d_in[11];
  const float* gb     = (const float*)d_in[12];
  const float* uv     = (const float*)d_in[13];
  const float* sup    = (const float*)d_in[14];

  float* out  = (float*)d_out;                  // (B,T,O) first
  float* traj = out + (size_t)B_N * T_N * O_N;  // then (B,T,H)

  rnn_fused<<<dim3(B_N), dim3(TPB), 0, stream>>>(
      input, noise, wi, unitwi, m_, n_, unitm, unitn, wo, h0, unith0, bias,
      gb, uv, sup, out, traj);
}

// Round 4
// 495.794 us; speedup vs baseline: 1.8838x; 1.8838x over previous
//
#include <hip/hip_runtime.h>

typedef float v2f __attribute__((ext_vector_type(2)));

// Problem constants (from reference)
constexpr int I_N = 3, H_N = 2048, O_N = 2, S_N = 4, G_N = 7;
constexpr int B_N = 32, T_N = 512;
constexpr int TPB = 512;          // threads per block (8 waves)
constexpr int EPT = H_N / TPB;    // 4 consecutive h-elements per thread
constexpr float ALPHA_C = 0.2f;
constexpr float NSTD_C = 0.05f;
constexpr float TWO_LOG2E = 2.885390081777927f;  // 2*log2(e)

// tanh(x) = 1 - 2/(exp2(2*log2e*x)+1); inf-safe both ends
__device__ __forceinline__ float fast_tanh(float x) {
  float e = __builtin_amdgcn_exp2f(x * TWO_LOG2E);
  return fmaf(-2.0f, __builtin_amdgcn_rcpf(e + 1.0f), 1.0f);
}

#define DPP_ADD(x, ctrl, rmask)                                                \
  x += __int_as_float(__builtin_amdgcn_update_dpp(                             \
      0, __float_as_int(x), (ctrl), (rmask), 0xf, true))

// Full 64-lane sum -> lane 63 (R1-proven ladder; row_shr moves data to HIGHER lanes)
__device__ __forceinline__ float wave_sum63(float x) {
  DPP_ADD(x, 0x111, 0xf);  // row_shr:1
  DPP_ADD(x, 0x112, 0xf);  // row_shr:2
  DPP_ADD(x, 0x114, 0xf);  // row_shr:4
  DPP_ADD(x, 0x118, 0xf);  // row_shr:8
  DPP_ADD(x, 0x142, 0xa);  // row_bcast15 -> lane31
  DPP_ADD(x, 0x143, 0xc);  // row_bcast31 -> lane63
  return x;
}

__device__ __forceinline__ float rfl(float v) {
  return __int_as_float(__builtin_amdgcn_readfirstlane(__float_as_int(v)));
}

__global__ __launch_bounds__(TPB) void rnn_fused(
    const float* __restrict__ input,   // (B,T,I)
    const float* __restrict__ noise,   // (B,T,H)
    const float* __restrict__ wi,      // (I,S,G)
    const float* __restrict__ unitwi,  // (I,S,1)
    const float* __restrict__ m_,      // (R,S,G)
    const float* __restrict__ n_,      // (R,S,G)
    const float* __restrict__ unitm,   // (R,S,1)
    const float* __restrict__ unitn,   // (R,S,1)
    const float* __restrict__ wo,      // (O,S,G)
    const float* __restrict__ h0,      // (S,G)
    const float* __restrict__ unith0,  // (S,1)
    const float* __restrict__ bias,    // (S,1)
    const float* __restrict__ gb,      // (G,H)
    const float* __restrict__ uv,      // (1,H)
    const float* __restrict__ sup,     // (S,H)
    float* __restrict__ out,           // (B,T,O)
    float* __restrict__ traj) {        // (B,T,H)
  const int tid = threadIdx.x;
  const int lane = tid & 63;
  const int wave = tid >> 6;
  const int b = blockIdx.x;
  const int hbase = tid * EPT;
  const int s = hbase >> 9;  // H/S = 512

  // Double-buffered wave partials: slots 0..7 live, 8..15 stay zero.
  __shared__ float4 parts[2][16];
  __shared__ float4 xs4[T_N];  // x_t staged as float4 (w unused)

  // ---- setup: per-element proxy constants ----
  float cn0[EPT], cn1[EPT], cm0[EPT], cm1[EPT];
  float cw0[EPT], cw1[EPT], cw2[EPT];
  float co0[EPT], co1[EPT], cb[EPT], hh_[EPT], r[EPT];

  for (int e = 0; e < EPT; ++e) {
    const int hh = hbase + e;
    float gbh[G_N];
#pragma unroll
    for (int g = 0; g < G_N; ++g) gbh[g] = gb[g * H_N + hh];
    const float uvh = uv[hh];
    const float sv = sup[s * H_N + hh];

    auto comb = [&](const float* p, const float* up, int k) {
      float acc = up[k * S_N + s] * uvh;
#pragma unroll
      for (int g = 0; g < G_N; ++g)
        acc = fmaf(p[(k * S_N + s) * G_N + g], gbh[g], acc);
      return acc * sv;
    };
    auto combNoU = [&](const float* p, int k) {
      float acc = 0.0f;
#pragma unroll
      for (int g = 0; g < G_N; ++g)
        acc = fmaf(p[(k * S_N + s) * G_N + g], gbh[g], acc);
      return acc * sv;
    };

    cn0[e] = comb(n_, unitn, 0);
    cn1[e] = comb(n_, unitn, 1);
    cm0[e] = ALPHA_C * comb(m_, unitm, 0);
    cm1[e] = ALPHA_C * comb(m_, unitm, 1);
    cw0[e] = ALPHA_C * comb(wi, unitwi, 0);
    cw1[e] = ALPHA_C * comb(wi, unitwi, 1);
    cw2[e] = ALPHA_C * comb(wi, unitwi, 2);
    co0[e] = combNoU(wo, 0);
    co1[e] = combNoU(wo, 1);
    cb[e] = bias[s] * uvh * sv;
    hh_[e] = comb(h0, unith0, 0);
    r[e] = fast_tanh(hh_[e]);
  }

  // packed layouts
  v2f cnp[EPT], cop[EPT];
  v2f cm0p[2], cm1p[2], cw0p[2], cw1p[2], cw2p[2], cbp[2];
#pragma unroll
  for (int e = 0; e < EPT; ++e) {
    cnp[e] = (v2f){cn0[e], cn1[e]};
    cop[e] = (v2f){co0[e], co1[e]};
  }
#pragma unroll
  for (int p2 = 0; p2 < 2; ++p2) {
    cm0p[p2] = (v2f){cm0[2 * p2], cm0[2 * p2 + 1]};
    cm1p[p2] = (v2f){cm1[2 * p2], cm1[2 * p2 + 1]};
    cw0p[p2] = (v2f){cw0[2 * p2], cw0[2 * p2 + 1]};
    cw1p[p2] = (v2f){cw1[2 * p2], cw1[2 * p2 + 1]};
    cw2p[p2] = (v2f){cw2[2 * p2], cw2[2 * p2 + 1]};
    cbp[p2] = (v2f){cb[2 * p2], cb[2 * p2 + 1]};
  }
  v2f h01 = (v2f){hh_[0], hh_[1]};
  v2f h23 = (v2f){hh_[2], hh_[3]};

  const float* zp = noise + ((size_t)b * T_N) * H_N + hbase;
  const float* xp = input + ((size_t)b * T_N) * I_N;
  float* tp = traj + ((size_t)b * T_N) * H_N + hbase;
  float* op = out + ((size_t)b * T_N) * O_N;

  // stage x into LDS (thread t handles timestep t; TPB == T_N)
  {
    const float* xq = xp + tid * I_N;
    xs4[tid] = make_float4(xq[0], xq[1], xq[2], 0.0f);
  }
  // zero the 8 dead slots of both partial buffers (once)
  if (tid < 16) parts[tid >> 3][8 + (tid & 7)] = make_float4(0.f, 0.f, 0.f, 0.f);

  // depth-2 z prefetch
  float4 z0 = *(const float4*)zp;
  float4 z1 = *(const float4*)(zp + H_N);

  __builtin_amdgcn_s_waitcnt(0xC07F);  // lgkmcnt(0)
  __builtin_amdgcn_s_barrier();
  __asm__ volatile("" ::: "memory");

  float4 xv = xs4[0];

  auto body = [&](int t, int pb) {
    // prefetch z_{t+2} (HBM) and x_{t+1} (LDS)
    const int tz = (t + 2 < T_N) ? t + 2 : T_N - 1;
    float4 zn = *(const float4*)(zp + (size_t)tz * H_N);
    const int tx = (t + 1 < T_N) ? t + 1 : T_N - 1;
    float4 xn = xs4[tx];

    // reduce-independent part of the update: bias + noise + x·wi
    v2f z01 = (v2f){z0.x, z0.y}, z23 = (v2f){z0.z, z0.w};
    v2f pre01 = cbp[0];
    pre01 += NSTD_C * z01;
    pre01 += xv.x * cw0p[0];
    pre01 += xv.y * cw1p[0];
    pre01 += xv.z * cw2p[0];
    v2f pre23 = cbp[1];
    pre23 += NSTD_C * z23;
    pre23 += xv.x * cw0p[1];
    pre23 += xv.y * cw1p[1];
    pre23 += xv.z * cw2p[1];

    // 4 dot-partials: a0,a1 (recurrence), o0,o1 (out_{t-1})
    v2f accA = (v2f){0.f, 0.f}, accO = (v2f){0.f, 0.f};
#pragma unroll
    for (int e = 0; e < EPT; ++e) {
      v2f rr = (v2f){r[e], r[e]};
      accA += rr * cnp[e];
      accO += rr * cop[e];
    }
    float pa0 = wave_sum63(accA.x);
    float pa1 = wave_sum63(accA.y);
    float po0 = wave_sum63(accO.x);
    float po1 = wave_sum63(accO.y);
    if (lane == 63) parts[pb][wave] = make_float4(pa0, pa1, po0, po1);

    __builtin_amdgcn_s_waitcnt(0xC07F);  // lgkmcnt(0) only
    __builtin_amdgcn_s_barrier();
    __asm__ volatile("" ::: "memory");

    // stage 2: one b128 read + 3 row_shl DPP adds -> lane0 = sum slots 0..7
    // (row_shl:N -> dest lane i reads lane i+N; bound_ctrl zeros past 15)
    float4 v = parts[pb][lane & 15];
    DPP_ADD(v.x, 0x101, 0xf); DPP_ADD(v.x, 0x102, 0xf); DPP_ADD(v.x, 0x104, 0xf);
    DPP_ADD(v.y, 0x101, 0xf); DPP_ADD(v.y, 0x102, 0xf); DPP_ADD(v.y, 0x104, 0xf);
    DPP_ADD(v.z, 0x101, 0xf); DPP_ADD(v.z, 0x102, 0xf); DPP_ADD(v.z, 0x104, 0xf);
    DPP_ADD(v.w, 0x101, 0xf); DPP_ADD(v.w, 0x102, 0xf); DPP_ADD(v.w, 0x104, 0xf);
    const float a0 = rfl(v.x);
    const float a1 = rfl(v.y);
    const float o0 = rfl(v.z);
    const float o1 = rfl(v.w);

    if (tid == 0 && t > 0) ((float2*)op)[t - 1] = make_float2(o0, o1);

    // h <- 0.8h + pre + a0*cm0 + a1*cm1
    h01 = 0.8f * h01 + pre01;
    h01 += a0 * cm0p[0];
    h01 += a1 * cm1p[0];
    h23 = 0.8f * h23 + pre23;
    h23 += a0 * cm0p[1];
    h23 += a1 * cm1p[1];

    *(float4*)(tp + (size_t)t * H_N) = make_float4(h01.x, h01.y, h23.x, h23.y);

    r[0] = fast_tanh(h01.x);
    r[1] = fast_tanh(h01.y);
    r[2] = fast_tanh(h23.x);
    r[3] = fast_tanh(h23.y);

    z0 = z1; z1 = zn; xv = xn;
  };

  for (int t = 0; t < T_N; t += 2) {
    body(t, 0);
    body(t + 1, 1);
  }

  // tail: out[T-1] = tanh(h_T) @ wo (parts[0] fully rewritten by all 8 waves)
  {
    v2f accO = (v2f){0.f, 0.f};
#pragma unroll
    for (int e = 0; e < EPT; ++e) {
      v2f rr = (v2f){r[e], r[e]};
      accO += rr * cop[e];
    }
    float po0 = wave_sum63(accO.x);
    float po1 = wave_sum63(accO.y);
    if (lane == 63) parts[0][wave] = make_float4(0.f, 0.f, po0, po1);
    __builtin_amdgcn_s_waitcnt(0xC07F);
    __builtin_amdgcn_s_barrier();
    __asm__ volatile("" ::: "memory");
    if (tid == 0) {
      float o0 = 0.f, o1 = 0.f;
#pragma unroll
      for (int w = 0; w < 8; ++w) {
        float4 pv = parts[0][w];
        o0 += pv.z;
        o1 += pv.w;
      }
      ((float2*)op)[T_N - 1] = make_float2(o0, o1);
    }
  }
}

extern "C" void kernel_launch(void* const* d_in, const int* in_sizes, int n_in,
                              void* d_out, int out_size, void* d_ws, size_t ws_size,
                              hipStream_t stream) {
  const float* input  = (const float*)d_in[0];
  const float* noise  = (const float*)d_in[1];
  const float* wi     = (const float*)d_in[2];
  const float* unitwi = (const float*)d_in[3];
  const float* m_     = (const float*)d_in[4];
  const float* n_     = (const float*)d_in[5];
  const float* unitm  = (const float*)d_in[6];
  const float* unitn  = (const float*)d_in[7];
  const float* wo     = (const float*)d_in[8];
  const float* h0     = (const float*)d_in[9];
  const float* unith0 = (const float*)d_in[10];
  const float* bias   = (const float*)d_in[11];
  const float* gb     = (const float*)d_in[12];
  const float* uv     = (const float*)d_in[13];
  const float* sup    = (const float*)d_in[14];

  float* out  = (float*)d_out;                  // (B,T,O) first
  float* traj = out + (size_t)B_N * T_N * O_N;  // then (B,T,H)

  rnn_fused<<<dim3(B_N), dim3(TPB), 0, stream>>>(
      input, noise, wi, unitwi, m_, n_, unitm, unitn, wo, h0, unith0, bias,
      gb, uv, sup, out, traj);
}

// Round 5
// 439.368 us; speedup vs baseline: 2.1257x; 1.1284x over previous
//
#include <hip/hip_runtime.h>

typedef float v2f __attribute__((ext_vector_type(2)));

// Problem constants (from reference)
constexpr int I_N = 3, H_N = 2048, O_N = 2, S_N = 4, G_N = 7;
constexpr int B_N = 32, T_N = 512;
constexpr int TPB = 512;          // threads per block (8 waves)
constexpr int EPT = H_N / TPB;    // 4 consecutive h-elements per thread
constexpr float ALPHA_C = 0.2f;
constexpr float NSTD_C = 0.05f;
constexpr float TWO_LOG2E = 2.885390081777927f;  // 2*log2(e)

// tanh(x) = 1 - 2/(exp2(2*log2e*x)+1); inf-safe both ends
__device__ __forceinline__ float fast_tanh(float x) {
  float e = __builtin_amdgcn_exp2f(x * TWO_LOG2E);
  return fmaf(-2.0f, __builtin_amdgcn_rcpf(e + 1.0f), 1.0f);
}

#define DPP_ADD(x, ctrl, rmask)                                                \
  x += __int_as_float(__builtin_amdgcn_update_dpp(                             \
      0, __float_as_int(x), (ctrl), (rmask), 0xf, true))

// Full 64-lane sum -> lane 63 (row_shr moves data to HIGHER lanes)
__device__ __forceinline__ float wave_sum63(float x) {
  DPP_ADD(x, 0x111, 0xf);  // row_shr:1
  DPP_ADD(x, 0x112, 0xf);  // row_shr:2
  DPP_ADD(x, 0x114, 0xf);  // row_shr:4
  DPP_ADD(x, 0x118, 0xf);  // row_shr:8
  DPP_ADD(x, 0x142, 0xa);  // row_bcast15 -> lane31
  DPP_ADD(x, 0x143, 0xc);  // row_bcast31 -> lane63
  return x;
}

__device__ __forceinline__ float rfl(float v) {
  return __int_as_float(__builtin_amdgcn_readfirstlane(__float_as_int(v)));
}

// ---------------- kernel0: precompute wo_full (H,2) into ws ----------------
__global__ __launch_bounds__(256) void wo_precomp(
    const float* __restrict__ wo, const float* __restrict__ gb,
    const float* __restrict__ sup, float2* __restrict__ ws2) {
  const int h = blockIdx.x * 256 + threadIdx.x;
  const int s = h >> 9;
  const float sv = sup[s * H_N + h];
  float c0 = 0.f, c1 = 0.f;
#pragma unroll
  for (int g = 0; g < G_N; ++g) {
    const float gv = gb[g * H_N + h];
    c0 = fmaf(wo[(0 * S_N + s) * G_N + g], gv, c0);
    c1 = fmaf(wo[(1 * S_N + s) * G_N + g], gv, c1);
  }
  ws2[h] = make_float2(c0 * sv, c1 * sv);
}

// ------------- kernel2: out[b,t] = tanh(traj[b,t,:]) @ wo_full -------------
__global__ __launch_bounds__(256) void out_proj(
    const float* __restrict__ traj, const float2* __restrict__ ws2,
    float* __restrict__ out) {
  const int blk = blockIdx.x;          // b*T + t
  const int tid = threadIdx.x;
  const int lane = tid & 63;
  const int wave = tid >> 6;
  const int hb = tid * 8;

  __shared__ float2 red[4];

  const float* tp = traj + (size_t)blk * H_N + hb;
  float4 t0 = *(const float4*)tp;
  float4 t1 = *(const float4*)(tp + 4);
  float2 c[8];
#pragma unroll
  for (int e = 0; e < 8; ++e) c[e] = ws2[hb + e];

  float hv[8] = {t0.x, t0.y, t0.z, t0.w, t1.x, t1.y, t1.z, t1.w};
  float p0 = 0.f, p1 = 0.f;
#pragma unroll
  for (int e = 0; e < 8; ++e) {
    const float rv = fast_tanh(hv[e]);
    p0 = fmaf(rv, c[e].x, p0);
    p1 = fmaf(rv, c[e].y, p1);
  }
  p0 = wave_sum63(p0);
  p1 = wave_sum63(p1);
  if (lane == 63) red[wave] = make_float2(p0, p1);
  __syncthreads();
  if (tid == 0) {
    float o0 = 0.f, o1 = 0.f;
#pragma unroll
    for (int w = 0; w < 4; ++w) {
      o0 += red[w].x;
      o1 += red[w].y;
    }
    ((float2*)out)[blk] = make_float2(o0, o1);
  }
}

// ----------------------- kernel1: the sequential RNN -----------------------
__global__ __launch_bounds__(TPB) void rnn_fused(
    const float* __restrict__ input,   // (B,T,I)
    const float* __restrict__ noise,   // (B,T,H)
    const float* __restrict__ wi,      // (I,S,G)
    const float* __restrict__ unitwi,  // (I,S,1)
    const float* __restrict__ m_,      // (R,S,G)
    const float* __restrict__ n_,      // (R,S,G)
    const float* __restrict__ unitm,   // (R,S,1)
    const float* __restrict__ unitn,   // (R,S,1)
    const float* __restrict__ h0,      // (S,G)
    const float* __restrict__ unith0,  // (S,1)
    const float* __restrict__ bias,    // (S,1)
    const float* __restrict__ gb,      // (G,H)
    const float* __restrict__ uv,      // (1,H)
    const float* __restrict__ sup,     // (S,H)
    float* __restrict__ traj) {        // (B,T,H)
  const int tid = threadIdx.x;
  const int lane = tid & 63;
  const int wave = tid >> 6;
  const int b = blockIdx.x;
  const int hbase = tid * EPT;
  const int s = hbase >> 9;  // H/S = 512

  // Double-buffered wave partials: slots 0..7 live, 8..15 stay zero.
  __shared__ float2 parts[2][16];
  __shared__ float4 xs4[T_N];  // x_t staged as float4 (w unused)

  // ---- setup: per-element proxy constants ----
  float cn0[EPT], cn1[EPT], cm0[EPT], cm1[EPT];
  float cw0[EPT], cw1[EPT], cw2[EPT];
  float cb[EPT], hh_[EPT], r[EPT];

  for (int e = 0; e < EPT; ++e) {
    const int hh = hbase + e;
    float gbh[G_N];
#pragma unroll
    for (int g = 0; g < G_N; ++g) gbh[g] = gb[g * H_N + hh];
    const float uvh = uv[hh];
    const float sv = sup[s * H_N + hh];

    auto comb = [&](const float* p, const float* up, int k) {
      float acc = up[k * S_N + s] * uvh;
#pragma unroll
      for (int g = 0; g < G_N; ++g)
        acc = fmaf(p[(k * S_N + s) * G_N + g], gbh[g], acc);
      return acc * sv;
    };

    cn0[e] = comb(n_, unitn, 0);
    cn1[e] = comb(n_, unitn, 1);
    cm0[e] = ALPHA_C * comb(m_, unitm, 0);
    cm1[e] = ALPHA_C * comb(m_, unitm, 1);
    cw0[e] = ALPHA_C * comb(wi, unitwi, 0);
    cw1[e] = ALPHA_C * comb(wi, unitwi, 1);
    cw2[e] = ALPHA_C * comb(wi, unitwi, 2);
    cb[e] = bias[s] * uvh * sv;
    hh_[e] = comb(h0, unith0, 0);
    r[e] = fast_tanh(hh_[e]);
  }

  // packed layouts
  v2f cnp[EPT];
  v2f cm0p[2], cm1p[2], cw0p[2], cw1p[2], cw2p[2], cbp[2];
#pragma unroll
  for (int e = 0; e < EPT; ++e) cnp[e] = (v2f){cn0[e], cn1[e]};
#pragma unroll
  for (int p2 = 0; p2 < 2; ++p2) {
    cm0p[p2] = (v2f){cm0[2 * p2], cm0[2 * p2 + 1]};
    cm1p[p2] = (v2f){cm1[2 * p2], cm1[2 * p2 + 1]};
    cw0p[p2] = (v2f){cw0[2 * p2], cw0[2 * p2 + 1]};
    cw1p[p2] = (v2f){cw1[2 * p2], cw1[2 * p2 + 1]};
    cw2p[p2] = (v2f){cw2[2 * p2], cw2[2 * p2 + 1]};
    cbp[p2] = (v2f){cb[2 * p2], cb[2 * p2 + 1]};
  }
  v2f h01 = (v2f){hh_[0], hh_[1]};
  v2f h23 = (v2f){hh_[2], hh_[3]};

  const float* zp = noise + ((size_t)b * T_N) * H_N + hbase;
  const float* xp = input + ((size_t)b * T_N) * I_N;
  float* tp = traj + ((size_t)b * T_N) * H_N + hbase;

  // stage x into LDS (thread t handles timestep t; TPB == T_N)
  {
    const float* xq = xp + tid * I_N;
    xs4[tid] = make_float4(xq[0], xq[1], xq[2], 0.0f);
  }
  // zero the 8 dead slots of both partial buffers (once)
  if (tid < 16) parts[tid >> 3][8 + (tid & 7)] = make_float2(0.f, 0.f);

  // depth-4 z prefetch ring
  float4 zr0 = *(const float4*)zp;
  float4 zr1 = *(const float4*)(zp + H_N);
  float4 zr2 = *(const float4*)(zp + 2 * (size_t)H_N);
  float4 zr3 = *(const float4*)(zp + 3 * (size_t)H_N);

  __builtin_amdgcn_s_waitcnt(0xC07F);  // lgkmcnt(0)
  __builtin_amdgcn_s_barrier();
  __asm__ volatile("" ::: "memory");

  float4 xv = xs4[0];

  auto body = [&](int t, int pb, float4& zslot) {
    // prefetch z_{t+4} (HBM, ring depth 4) and x_{t+1} (LDS)
    const float4 z0 = zslot;
    const int tz = (t + 4 < T_N) ? t + 4 : T_N - 1;
    float4 zn = *(const float4*)(zp + (size_t)tz * H_N);
    const int tx = (t + 1 < T_N) ? t + 1 : T_N - 1;
    float4 xn = xs4[tx];

    // reduce-independent part of the update: bias + noise + x·wi
    v2f z01 = (v2f){z0.x, z0.y}, z23 = (v2f){z0.z, z0.w};
    v2f pre01 = cbp[0];
    pre01 += NSTD_C * z01;
    pre01 += xv.x * cw0p[0];
    pre01 += xv.y * cw1p[0];
    pre01 += xv.z * cw2p[0];
    v2f pre23 = cbp[1];
    pre23 += NSTD_C * z23;
    pre23 += xv.x * cw0p[1];
    pre23 += xv.y * cw1p[1];
    pre23 += xv.z * cw2p[1];

    // 2 dot-partials: a0,a1 (recurrence only; output proj moved to out_proj)
    v2f accA = (v2f){0.f, 0.f};
#pragma unroll
    for (int e = 0; e < EPT; ++e) {
      v2f rr = (v2f){r[e], r[e]};
      accA += rr * cnp[e];
    }
    float pa0 = wave_sum63(accA.x);
    float pa1 = wave_sum63(accA.y);
    if (lane == 63) parts[pb][wave] = make_float2(pa0, pa1);

    __builtin_amdgcn_s_waitcnt(0xC07F);  // lgkmcnt(0) only
    __builtin_amdgcn_s_barrier();
    __asm__ volatile("" ::: "memory");

    // stage 2: one b64 read + 3 row_shl DPP adds -> lane0 = sum slots 0..7
    float2 v = parts[pb][lane & 15];
    DPP_ADD(v.x, 0x101, 0xf); DPP_ADD(v.x, 0x102, 0xf); DPP_ADD(v.x, 0x104, 0xf);
    DPP_ADD(v.y, 0x101, 0xf); DPP_ADD(v.y, 0x102, 0xf); DPP_ADD(v.y, 0x104, 0xf);
    const float a0 = rfl(v.x);
    const float a1 = rfl(v.y);

    // h <- 0.8h + pre + a0*cm0 + a1*cm1
    h01 = 0.8f * h01 + pre01;
    h01 += a0 * cm0p[0];
    h01 += a1 * cm1p[0];
    h23 = 0.8f * h23 + pre23;
    h23 += a0 * cm0p[1];
    h23 += a1 * cm1p[1];

    *(float4*)(tp + (size_t)t * H_N) = make_float4(h01.x, h01.y, h23.x, h23.y);

    r[0] = fast_tanh(h01.x);
    r[1] = fast_tanh(h01.y);
    r[2] = fast_tanh(h23.x);
    r[3] = fast_tanh(h23.y);

    zslot = zn;
    xv = xn;
  };

  for (int t = 0; t < T_N; t += 4) {
    body(t, 0, zr0);
    body(t + 1, 1, zr1);
    body(t + 2, 0, zr2);
    body(t + 3, 1, zr3);
  }
}

extern "C" void kernel_launch(void* const* d_in, const int* in_sizes, int n_in,
                              void* d_out, int out_size, void* d_ws, size_t ws_size,
                              hipStream_t stream) {
  const float* input  = (const float*)d_in[0];
  const float* noise  = (const float*)d_in[1];
  const float* wi     = (const float*)d_in[2];
  const float* unitwi = (const float*)d_in[3];
  const float* m_     = (const float*)d_in[4];
  const float* n_     = (const float*)d_in[5];
  const float* unitm  = (const float*)d_in[6];
  const float* unitn  = (const float*)d_in[7];
  const float* wo     = (const float*)d_in[8];
  const float* h0     = (const float*)d_in[9];
  const float* unith0 = (const float*)d_in[10];
  const float* bias   = (const float*)d_in[11];
  const float* gb     = (const float*)d_in[12];
  const float* uv     = (const float*)d_in[13];
  const float* sup    = (const float*)d_in[14];

  float* out  = (float*)d_out;                  // (B,T,O) first
  float* traj = out + (size_t)B_N * T_N * O_N;  // then (B,T,H)
  float2* ws2 = (float2*)d_ws;                  // wo_full (H,2)

  wo_precomp<<<dim3(H_N / 256), dim3(256), 0, stream>>>(wo, gb, sup, ws2);
  rnn_fused<<<dim3(B_N), dim3(TPB), 0, stream>>>(
      input, noise, wi, unitwi, m_, n_, unitm, unitn, h0, unith0, bias,
      gb, uv, sup, traj);
  out_proj<<<dim3(B_N * T_N), dim3(256), 0, stream>>>(traj, ws2, out);
}

// Round 6
// 433.455 us; speedup vs baseline: 2.1547x; 1.0136x over previous
//
#include <hip/hip_runtime.h>

typedef float v2f __attribute__((ext_vector_type(2)));

// Problem constants (from reference)
constexpr int I_N = 3, H_N = 2048, O_N = 2, S_N = 4, G_N = 7;
constexpr int B_N = 32, T_N = 512;
constexpr int TPB = 512;          // threads per block (8 waves)
constexpr int EPT = H_N / TPB;    // 4 consecutive h-elements per thread
constexpr float ALPHA_C = 0.2f;
constexpr float NSTD_C = 0.05f;
constexpr float TWO_LOG2E = 2.885390081777927f;  // 2*log2(e)

// tanh(x) = 1 - 2/(exp2(2*log2e*x)+1); inf-safe both ends
__device__ __forceinline__ float fast_tanh(float x) {
  float e = __builtin_amdgcn_exp2f(x * TWO_LOG2E);
  return fmaf(-2.0f, __builtin_amdgcn_rcpf(e + 1.0f), 1.0f);
}

#define DPP_ADD(x, ctrl, rmask)                                                \
  x += __int_as_float(__builtin_amdgcn_update_dpp(                             \
      0, __float_as_int(x), (ctrl), (rmask), 0xf, true))

// Full 64-lane sum -> lane 63 (row_shr moves data to HIGHER lanes)
__device__ __forceinline__ float wave_sum63(float x) {
  DPP_ADD(x, 0x111, 0xf);  // row_shr:1
  DPP_ADD(x, 0x112, 0xf);  // row_shr:2
  DPP_ADD(x, 0x114, 0xf);  // row_shr:4
  DPP_ADD(x, 0x118, 0xf);  // row_shr:8
  DPP_ADD(x, 0x142, 0xa);  // row_bcast15 -> lane31
  DPP_ADD(x, 0x143, 0xc);  // row_bcast31 -> lane63
  return x;
}

__device__ __forceinline__ float rfl(float v) {
  return __int_as_float(__builtin_amdgcn_readfirstlane(__float_as_int(v)));
}

// ---------------- kernel0: precompute wo_full (H,2) into ws ----------------
__global__ __launch_bounds__(256) void wo_precomp(
    const float* __restrict__ wo, const float* __restrict__ gb,
    const float* __restrict__ sup, float2* __restrict__ ws2) {
  const int h = blockIdx.x * 256 + threadIdx.x;
  const int s = h >> 9;
  const float sv = sup[s * H_N + h];
  float c0 = 0.f, c1 = 0.f;
#pragma unroll
  for (int g = 0; g < G_N; ++g) {
    const float gv = gb[g * H_N + h];
    c0 = fmaf(wo[(0 * S_N + s) * G_N + g], gv, c0);
    c1 = fmaf(wo[(1 * S_N + s) * G_N + g], gv, c1);
  }
  ws2[h] = make_float2(c0 * sv, c1 * sv);
}

// ------------- kernel2: out[b,t] = tanh(traj[b,t,:]) @ wo_full -------------
__global__ __launch_bounds__(256) void out_proj(
    const float* __restrict__ traj, const float2* __restrict__ ws2,
    float* __restrict__ out) {
  const int blk = blockIdx.x;          // b*T + t
  const int tid = threadIdx.x;
  const int lane = tid & 63;
  const int wave = tid >> 6;
  const int hb = tid * 8;

  __shared__ float2 red[4];

  const float* tp = traj + (size_t)blk * H_N + hb;
  float4 t0 = *(const float4*)tp;
  float4 t1 = *(const float4*)(tp + 4);
  float2 c[8];
#pragma unroll
  for (int e = 0; e < 8; ++e) c[e] = ws2[hb + e];

  float hv[8] = {t0.x, t0.y, t0.z, t0.w, t1.x, t1.y, t1.z, t1.w};
  float p0 = 0.f, p1 = 0.f;
#pragma unroll
  for (int e = 0; e < 8; ++e) {
    const float rv = fast_tanh(hv[e]);
    p0 = fmaf(rv, c[e].x, p0);
    p1 = fmaf(rv, c[e].y, p1);
  }
  p0 = wave_sum63(p0);
  p1 = wave_sum63(p1);
  if (lane == 63) red[wave] = make_float2(p0, p1);
  __syncthreads();
  if (tid == 0) {
    float o0 = 0.f, o1 = 0.f;
#pragma unroll
    for (int w = 0; w < 4; ++w) {
      o0 += red[w].x;
      o1 += red[w].y;
    }
    ((float2*)out)[blk] = make_float2(o0, o1);
  }
}

// ----------------------- kernel1: the sequential RNN -----------------------
__global__ __launch_bounds__(TPB) void rnn_fused(
    const float* __restrict__ input,   // (B,T,I)
    const float* __restrict__ noise,   // (B,T,H)
    const float* __restrict__ wi,      // (I,S,G)
    const float* __restrict__ unitwi,  // (I,S,1)
    const float* __restrict__ m_,      // (R,S,G)
    const float* __restrict__ n_,      // (R,S,G)
    const float* __restrict__ unitm,   // (R,S,1)
    const float* __restrict__ unitn,   // (R,S,1)
    const float* __restrict__ h0,      // (S,G)
    const float* __restrict__ unith0,  // (S,1)
    const float* __restrict__ bias,    // (S,1)
    const float* __restrict__ gb,      // (G,H)
    const float* __restrict__ uv,      // (1,H)
    const float* __restrict__ sup,     // (S,H)
    float* __restrict__ traj) {        // (B,T,H)
  const int tid = threadIdx.x;
  const int lane = tid & 63;
  const int wave = tid >> 6;
  const int b = blockIdx.x;
  const int hbase = tid * EPT;
  const int s = hbase >> 9;  // H/S = 512

  // Double-buffered wave partials: slots 0..7 live, 8..15 stay zero.
  __shared__ float2 parts[2][16];
  __shared__ float4 xs4[T_N];  // x_t staged as float4 (w unused)

  // ---- setup: per-element proxy constants ----
  float cn0[EPT], cn1[EPT], cm0[EPT], cm1[EPT];
  float cw0[EPT], cw1[EPT], cw2[EPT];
  float cb[EPT], hh_[EPT], r[EPT];

  for (int e = 0; e < EPT; ++e) {
    const int hh = hbase + e;
    float gbh[G_N];
#pragma unroll
    for (int g = 0; g < G_N; ++g) gbh[g] = gb[g * H_N + hh];
    const float uvh = uv[hh];
    const float sv = sup[s * H_N + hh];

    auto comb = [&](const float* p, const float* up, int k) {
      float acc = up[k * S_N + s] * uvh;
#pragma unroll
      for (int g = 0; g < G_N; ++g)
        acc = fmaf(p[(k * S_N + s) * G_N + g], gbh[g], acc);
      return acc * sv;
    };

    cn0[e] = comb(n_, unitn, 0);
    cn1[e] = comb(n_, unitn, 1);
    cm0[e] = ALPHA_C * comb(m_, unitm, 0);
    cm1[e] = ALPHA_C * comb(m_, unitm, 1);
    cw0[e] = ALPHA_C * comb(wi, unitwi, 0);
    cw1[e] = ALPHA_C * comb(wi, unitwi, 1);
    cw2[e] = ALPHA_C * comb(wi, unitwi, 2);
    cb[e] = bias[s] * uvh * sv;
    hh_[e] = comb(h0, unith0, 0);
    r[e] = fast_tanh(hh_[e]);
  }

  // packed layouts
  v2f cnp[EPT];
  v2f cm0p[2], cm1p[2], cw0p[2], cw1p[2], cw2p[2], cbp[2];
#pragma unroll
  for (int e = 0; e < EPT; ++e) cnp[e] = (v2f){cn0[e], cn1[e]};
#pragma unroll
  for (int p2 = 0; p2 < 2; ++p2) {
    cm0p[p2] = (v2f){cm0[2 * p2], cm0[2 * p2 + 1]};
    cm1p[p2] = (v2f){cm1[2 * p2], cm1[2 * p2 + 1]};
    cw0p[p2] = (v2f){cw0[2 * p2], cw0[2 * p2 + 1]};
    cw1p[p2] = (v2f){cw1[2 * p2], cw1[2 * p2 + 1]};
    cw2p[p2] = (v2f){cw2[2 * p2], cw2[2 * p2 + 1]};
    cbp[p2] = (v2f){cb[2 * p2], cb[2 * p2 + 1]};
  }
  v2f h01 = (v2f){hh_[0], hh_[1]};
  v2f h23 = (v2f){hh_[2], hh_[3]};

  const float* zp = noise + ((size_t)b * T_N) * H_N + hbase;
  const float* xp = input + ((size_t)b * T_N) * I_N;
  float* tp = traj + ((size_t)b * T_N) * H_N + hbase;

  // stage x into LDS (thread t handles timestep t; TPB == T_N)
  {
    const float* xq = xp + tid * I_N;
    xs4[tid] = make_float4(xq[0], xq[1], xq[2], 0.0f);
  }
  // zero the 8 dead slots of both partial buffers (once)
  if (tid < 16) parts[tid >> 3][8 + (tid & 7)] = make_float2(0.f, 0.f);

  // depth-8 z prefetch ring (keeps 8 x 16B loads in flight per thread)
  float4 zr0 = *(const float4*)zp;
  float4 zr1 = *(const float4*)(zp + 1 * (size_t)H_N);
  float4 zr2 = *(const float4*)(zp + 2 * (size_t)H_N);
  float4 zr3 = *(const float4*)(zp + 3 * (size_t)H_N);
  float4 zr4 = *(const float4*)(zp + 4 * (size_t)H_N);
  float4 zr5 = *(const float4*)(zp + 5 * (size_t)H_N);
  float4 zr6 = *(const float4*)(zp + 6 * (size_t)H_N);
  float4 zr7 = *(const float4*)(zp + 7 * (size_t)H_N);

  __builtin_amdgcn_s_waitcnt(0xC07F);  // lgkmcnt(0)
  __builtin_amdgcn_s_barrier();
  __asm__ volatile("" ::: "memory");

  float4 xv = xs4[0];

  auto body = [&](int t, int pb, float4& zslot) {
    // prefetch z_{t+8} (HBM, ring depth 8) and x_{t+1} (LDS)
    const float4 z0 = zslot;
    const int tz = (t + 8 < T_N) ? t + 8 : T_N - 1;
    float4 zn = *(const float4*)(zp + (size_t)tz * H_N);
    const int tx = (t + 1 < T_N) ? t + 1 : T_N - 1;
    float4 xn = xs4[tx];

    // reduce-independent part of the update: bias + noise + x·wi
    v2f z01 = (v2f){z0.x, z0.y}, z23 = (v2f){z0.z, z0.w};
    v2f pre01 = cbp[0];
    pre01 += NSTD_C * z01;
    pre01 += xv.x * cw0p[0];
    pre01 += xv.y * cw1p[0];
    pre01 += xv.z * cw2p[0];
    v2f pre23 = cbp[1];
    pre23 += NSTD_C * z23;
    pre23 += xv.x * cw0p[1];
    pre23 += xv.y * cw1p[1];
    pre23 += xv.z * cw2p[1];

    // 2 dot-partials: a0,a1 (recurrence only; output proj in out_proj)
    v2f accA = (v2f){0.f, 0.f};
#pragma unroll
    for (int e = 0; e < EPT; ++e) {
      v2f rr = (v2f){r[e], r[e]};
      accA += rr * cnp[e];
    }
    float pa0 = wave_sum63(accA.x);
    float pa1 = wave_sum63(accA.y);
    if (lane == 63) parts[pb][wave] = make_float2(pa0, pa1);

    __builtin_amdgcn_s_waitcnt(0xC07F);  // lgkmcnt(0) only
    __builtin_amdgcn_s_barrier();
    __asm__ volatile("" ::: "memory");

    // stage 2: one b64 read + 3 row_shl DPP adds -> lane0 = sum slots 0..7
    float2 v = parts[pb][lane & 15];
    DPP_ADD(v.x, 0x101, 0xf); DPP_ADD(v.x, 0x102, 0xf); DPP_ADD(v.x, 0x104, 0xf);
    DPP_ADD(v.y, 0x101, 0xf); DPP_ADD(v.y, 0x102, 0xf); DPP_ADD(v.y, 0x104, 0xf);
    const float a0 = rfl(v.x);
    const float a1 = rfl(v.y);

    // h <- 0.8h + pre + a0*cm0 + a1*cm1
    h01 = 0.8f * h01 + pre01;
    h01 += a0 * cm0p[0];
    h01 += a1 * cm1p[0];
    h23 = 0.8f * h23 + pre23;
    h23 += a0 * cm0p[1];
    h23 += a1 * cm1p[1];

    *(float4*)(tp + (size_t)t * H_N) = make_float4(h01.x, h01.y, h23.x, h23.y);

    r[0] = fast_tanh(h01.x);
    r[1] = fast_tanh(h01.y);
    r[2] = fast_tanh(h23.x);
    r[3] = fast_tanh(h23.y);

    zslot = zn;
    xv = xn;
  };

  for (int t = 0; t < T_N; t += 8) {
    body(t, 0, zr0);
    body(t + 1, 1, zr1);
    body(t + 2, 0, zr2);
    body(t + 3, 1, zr3);
    body(t + 4, 0, zr4);
    body(t + 5, 1, zr5);
    body(t + 6, 0, zr6);
    body(t + 7, 1, zr7);
  }
}

extern "C" void kernel_launch(void* const* d_in, const int* in_sizes, int n_in,
                              void* d_out, int out_size, void* d_ws, size_t ws_size,
                              hipStream_t stream) {
  const float* input  = (const float*)d_in[0];
  const float* noise  = (const float*)d_in[1];
  const float* wi     = (const float*)d_in[2];
  const float* unitwi = (const float*)d_in[3];
  const float* m_     = (const float*)d_in[4];
  const float* n_     = (const float*)d_in[5];
  const float* unitm  = (const float*)d_in[6];
  const float* unitn  = (const float*)d_in[7];
  const float* wo     = (const float*)d_in[8];
  const float* h0     = (const float*)d_in[9];
  const float* unith0 = (const float*)d_in[10];
  const float* bias   = (const float*)d_in[11];
  const float* gb     = (const float*)d_in[12];
  const float* uv     = (const float*)d_in[13];
  const float* sup    = (const float*)d_in[14];

  float* out  = (float*)d_out;                  // (B,T,O) first
  float* traj = out + (size_t)B_N * T_N * O_N;  // then (B,T,H)
  float2* ws2 = (float2*)d_ws;                  // wo_full (H,2)

  wo_precomp<<<dim3(H_N / 256), dim3(256), 0, stream>>>(wo, gb, sup, ws2);
  rnn_fused<<<dim3(B_N), dim3(TPB), 0, stream>>>(
      input, noise, wi, unitwi, m_, n_, unitm, unitn, h0, unith0, bias,
      gb, uv, sup, traj);
  out_proj<<<dim3(B_N * T_N), dim3(256), 0, stream>>>(traj, ws2, out);
}